// Round 9
// baseline (2978.070 us; speedup 1.0000x reference)
//
#include <hip/hip_runtime.h>

#define T_STEPS 512
#define BATCH   256
#define N_INP   128
#define N_HID   512
#define N_OUT   10

#define DT_C     0.042f
#define GAMMA_C  2.7f
#define EPS_C    4.7f

#define NWG        64      // 8 m-groups (32 rows) x 8 n-tiles (64 cols)
#define WG_THREADS 512     // 8 waves, 8-way K-split

typedef short          s16x8  __attribute__((ext_vector_type(8)));
typedef float          f32x16 __attribute__((ext_vector_type(16)));
typedef float          f32x4  __attribute__((ext_vector_type(4)));
typedef unsigned short u16x4  __attribute__((ext_vector_type(4)));
typedef unsigned long long u64;

__device__ inline unsigned short f2bf(float f) {
  union { float f; unsigned u; } v; v.f = f;
  unsigned r = v.u + 0x7fffu + ((v.u >> 16) & 1u);   // RNE
  return (unsigned short)(r >> 16);
}
__device__ inline float bf2f(unsigned short h) {
  union { unsigned u; float f; } v; v.u = ((unsigned)h) << 16;
  return v.f;
}

// agent-scope relaxed store: write-through to the coherence point (IC). Proven R4-R8.
__device__ inline void pub8(unsigned short* p, u16x4 v) {
  union { u16x4 v; u64 q; } u; u.v = v;
  __hip_atomic_store((u64*)p, u.q, __ATOMIC_RELAXED, __HIP_MEMORY_SCOPE_AGENT);
}

// 8 coherent 16B loads + waitcnt fused in ONE asm block (R6 lesson). Outputs
// earlyclobber vs the address pair.
#define STATE_LD8(HB, HP)                                                    \
  asm volatile(                                                              \
    "global_load_dwordx4 %0, %8, off sc0 sc1\n\t"                            \
    "global_load_dwordx4 %1, %8, off offset:32 sc0 sc1\n\t"                  \
    "global_load_dwordx4 %2, %8, off offset:64 sc0 sc1\n\t"                  \
    "global_load_dwordx4 %3, %8, off offset:96 sc0 sc1\n\t"                  \
    "global_load_dwordx4 %4, %8, off offset:128 sc0 sc1\n\t"                 \
    "global_load_dwordx4 %5, %8, off offset:160 sc0 sc1\n\t"                 \
    "global_load_dwordx4 %6, %8, off offset:192 sc0 sc1\n\t"                 \
    "global_load_dwordx4 %7, %8, off offset:224 sc0 sc1\n\t"                 \
    "s_waitcnt vmcnt(0)"                                                     \
    : "=&v"(HB[0]), "=&v"(HB[1]), "=&v"(HB[2]), "=&v"(HB[3]),                \
      "=&v"(HB[4]), "=&v"(HB[5]), "=&v"(HB[6]), "=&v"(HB[7])                 \
    : "v"(HP)                                                                \
    : "memory")

// Persistent recurrent kernel (plain launch; 64 blocks => co-resident).
// Hbf: double-buffered published state, bf16 [2][256][1024]; col c<512 = hz[c]
//      (W row 128+c), col 512+c = hy[c] (W row 640+c).
// Flags: per (group mi, producer WG ni, producer wave w) epoch words:
//      flags_ws + mi*128 + ni*8 + w. Wave w's flag covers rows 4w..4w+3 of the
//      producer's 64-col tile, set after a WAVE-level vmcnt drain of its
//      publishes (no post-publish workgroup barrier).
__global__ __launch_bounds__(WG_THREADS, 2) void cornn_kernel(
    const float* __restrict__ x, const float* __restrict__ W,
    const float* __restrict__ bias, unsigned short* __restrict__ Hbf,
    float* __restrict__ Hy32, unsigned* __restrict__ flags_ws) {
  const int tid   = threadIdx.x;
  const int lane  = tid & 63;
  const int ks    = tid >> 6;        // wave id 0..7 (8-way K-split)
  const int half  = lane >> 5;       // A/B frag k-half
  const int half8 = half << 3;
  const int lcol  = lane & 31;
  const int mi    = blockIdx.x & 7;  // row group
  const int ni    = blockIdx.x >> 3; // 64-col tile, 0..7
  const int rowA  = (mi << 5) + lcol;

  unsigned* gflags = flags_ws + mi * 128;   // 64 dwords used per group

  __shared__ float sC[8][2048];   // K-split partials (32 rows x 64 cols), 64 KB
  __shared__ float sB[64];

  // ---- stage W in registers: state 8 chunks/wave x 2 col-tiles (hi+lo),
  //      x 1 chunk/wave x 2 col-tiles (hi+lo) ----
  s16x8 whi0[8], wlo0[8], whi1[8], wlo1[8];
  s16x8 wxhi0, wxlo0, wxhi1, wxlo1;
  const int c0t = (ni << 6) + lcol;      // col tile 0
  #pragma unroll
  for (int i = 0; i < 8; ++i) {
    const int wr = 128 + (ks << 7) + i * 16 + half8;
    const float* wp0 = W + (size_t)wr * N_HID + c0t;
    s16x8 hi0, lo0, hi1, lo1;
    #pragma unroll
    for (int j = 0; j < 8; ++j) {
      float f0 = wp0[(size_t)j * N_HID];
      float f1 = wp0[(size_t)j * N_HID + 32];
      unsigned short h0 = f2bf(f0), h1 = f2bf(f1);
      hi0[j] = (short)h0;  lo0[j] = (short)f2bf(f0 - bf2f(h0));
      hi1[j] = (short)h1;  lo1[j] = (short)f2bf(f1 - bf2f(h1));
    }
    whi0[i] = hi0; wlo0[i] = lo0; whi1[i] = hi1; wlo1[i] = lo1;
  }
  {
    const int wr = (ks << 4) + half8;    // x chunk ks: k = ks*16
    const float* wp0 = W + (size_t)wr * N_HID + c0t;
    s16x8 hi0, lo0, hi1, lo1;
    #pragma unroll
    for (int j = 0; j < 8; ++j) {
      float f0 = wp0[(size_t)j * N_HID];
      float f1 = wp0[(size_t)j * N_HID + 32];
      unsigned short h0 = f2bf(f0), h1 = f2bf(f1);
      hi0[j] = (short)h0;  lo0[j] = (short)f2bf(f0 - bf2f(h0));
      hi1[j] = (short)h1;  lo1[j] = (short)f2bf(f1 - bf2f(h1));
    }
    wxhi0 = hi0; wxlo0 = lo0; wxhi1 = hi1; wxlo1 = lo1;
  }
  if (tid < 64) sB[tid] = bias[(ni << 6) + tid];

  // ---- per-thread fp32 state (4 cols each; 512 thr x 4 = 32 rows x 64 cols) ----
  const int e0   = tid << 2;
  const int rowL = e0 >> 6, c0 = e0 & 63;
  const int rowG = (mi << 5) + rowL;
  const int colG = (ni << 6) + c0;
  f32x4 hz = {0.f, 0.f, 0.f, 0.f};
  f32x4 hy = {0.f, 0.f, 0.f, 0.f};

  // state-read base pointers (per lane), one per buffer
  const unsigned short* hb2[2];
  hb2[0] = Hbf + (size_t)rowA * 1024 + (ks << 7) + half8;
  hb2[1] = hb2[0] + 256 * 1024;
  // publish pointers (per thread), one per buffer
  unsigned short* wz[2];
  unsigned short* wy[2];
  wz[0] = Hbf + (size_t)rowG * 1024 + colG;       wz[1] = wz[0] + 256 * 1024;
  wy[0] = wz[0] + 512;                            wy[1] = wz[1] + 512;

  // poll setup: wave ks's 128-col k-range is produced by WGs p0, p0+1; lanes
  // 0..15 poll flags (p0 + (l>>3), wave l&7). Own-WG flags are polled too —
  // required for own-publish visibility now that there is no post-publish
  // barrier (own wave drains before its flag, same as remote).
  const int pl = lane & 15;
  const unsigned* fpoll = gflags + (2 * (ks & 3) + (pl >> 3)) * 8 + (pl & 7);
  const bool plane = (lane >= 16);   // lanes >=16 auto-pass the ballot
  unsigned* myflag = gflags + ni * 8 + ks;

  // x software pipeline: hold x(t) in registers across the iteration
  const float* xbase = x + (size_t)rowA * N_INP + (ks << 4) + half8;
  f32x4 xa0 = *reinterpret_cast<const f32x4*>(xbase);
  f32x4 xa1 = *reinterpret_cast<const f32x4*>(xbase + 4);

  __syncthreads();   // sB visible

  for (int t = 0; t < T_STEPS; ++t) {
    f32x16 acc0 = {};
    f32x16 acc1 = {};

    // ---- x-part from held registers (no load wait on the pre-poll path) ----
    {
      s16x8 ahi, alo;
      #pragma unroll
      for (int j = 0; j < 4; ++j) {
        float f0 = xa0[j], f1 = xa1[j];
        unsigned short h0 = f2bf(f0), h1 = f2bf(f1);
        ahi[j]     = (short)h0;  ahi[j + 4] = (short)h1;
        alo[j]     = (short)f2bf(f0 - bf2f(h0));
        alo[j + 4] = (short)f2bf(f1 - bf2f(h1));
      }
      acc0 = __builtin_amdgcn_mfma_f32_32x32x16_bf16(ahi, wxhi0, acc0, 0, 0, 0);
      acc0 = __builtin_amdgcn_mfma_f32_32x32x16_bf16(ahi, wxlo0, acc0, 0, 0, 0);
      acc0 = __builtin_amdgcn_mfma_f32_32x32x16_bf16(alo, wxhi0, acc0, 0, 0, 0);
      acc1 = __builtin_amdgcn_mfma_f32_32x32x16_bf16(ahi, wxhi1, acc1, 0, 0, 0);
      acc1 = __builtin_amdgcn_mfma_f32_32x32x16_bf16(ahi, wxlo1, acc1, 0, 0, 0);
      acc1 = __builtin_amdgcn_mfma_f32_32x32x16_bf16(alo, wxhi1, acc1, 0, 0, 0);
    }

    if (t > 0) {
      // ---- pipelined 2-deep poll (detect ~1.1 RT instead of 1.5-2 RT).
      // waitcnt asms carry the polled value as "+v" so the ballot cannot be
      // scheduled between load and wait (R5 lesson). ----
      const unsigned ep = (unsigned)t;
      unsigned v0, v1;
      asm volatile("global_load_dword %0, %1, off sc0 sc1"
                   : "=v"(v0) : "v"(fpoll) : "memory");
      asm volatile("global_load_dword %0, %1, off sc0 sc1"
                   : "=v"(v1) : "v"(fpoll) : "memory");
      for (;;) {
        asm volatile("s_waitcnt vmcnt(1)" : "+v"(v0) :: "memory");
        if (__ballot(plane | (v0 >= ep)) == ~0ull) break;
        asm volatile("global_load_dword %0, %1, off sc0 sc1"
                     : "=v"(v0) : "v"(fpoll) : "memory");
        asm volatile("s_waitcnt vmcnt(1)" : "+v"(v1) :: "memory");
        if (__ballot(plane | (v1 >= ep)) == ~0ull) break;
        asm volatile("global_load_dword %0, %1, off sc0 sc1"
                     : "=v"(v1) : "v"(fpoll) : "memory");
      }

      // ---- state part: 8 pipelined coherent 16B loads, ONE round-trip ----
      const unsigned short* hp = hb2[t & 1];
      f32x4 hbuf[8];
      STATE_LD8(hbuf, hp);
      #pragma unroll
      for (int i = 0; i < 8; ++i) {
        union { f32x4 f; s16x8 s; } u; u.f = hbuf[i];
        acc0 = __builtin_amdgcn_mfma_f32_32x32x16_bf16(u.s, whi0[i], acc0, 0, 0, 0);
        acc0 = __builtin_amdgcn_mfma_f32_32x32x16_bf16(u.s, wlo0[i], acc0, 0, 0, 0);
        acc1 = __builtin_amdgcn_mfma_f32_32x32x16_bf16(u.s, whi1[i], acc1, 0, 0, 0);
        acc1 = __builtin_amdgcn_mfma_f32_32x32x16_bf16(u.s, wlo1[i], acc1, 0, 0, 0);
      }
    }

    // ---- prefetch x(t+1) into held regs (fills during barriers/next wait) ----
    {
      const int tn = (t < T_STEPS - 1) ? t + 1 : t;
      const float* xp = xbase + (size_t)tn * (BATCH * N_INP);
      xa0 = *reinterpret_cast<const f32x4*>(xp);
      xa1 = *reinterpret_cast<const f32x4*>(xp + 4);
    }

    // ---- K-split partials (C/D layout: col=lane&31, row=(r&3)+8*(r>>2)+4*half) ----
    #pragma unroll
    for (int r = 0; r < 16; ++r) {
      const int rowL_r = (r & 3) + ((r >> 2) << 3) + (half << 2);
      sC[ks][rowL_r * 64 + lcol]      = acc0[r];
      sC[ks][rowL_r * 64 + 32 + lcol] = acc1[r];
    }
    __syncthreads();                 // sync1: partials ready

    // ---- reduce (8-way) ----
    f32x4 s = *reinterpret_cast<f32x4*>(&sC[0][e0]);
    #pragma unroll
    for (int w = 1; w < 8; ++w) s += *reinterpret_cast<f32x4*>(&sC[w][e0]);
    __syncthreads();                 // sync2: sC reads done (guards next-step writes)

    // ---- tanh + state update + publish + WAVE-level drain + per-wave flag ----
    {
      u16x4 pz, py;
      #pragma unroll
      for (int j = 0; j < 4; ++j) {
        float pre = tanhf(s[j] + sB[c0 + j]);
        float z = hz[j] + DT_C * (pre - GAMMA_C * hy[j] - EPS_C * hz[j]);
        float y = hy[j] + DT_C * z;
        hz[j] = z; hy[j] = y;
        pz[j] = f2bf(z); py[j] = f2bf(y);
      }
      const int wb = (t & 1) ^ 1;
      pub8(wz[wb], pz);
      pub8(wy[wb], py);
    }
    asm volatile("s_waitcnt vmcnt(0)" ::: "memory");   // this wave's publishes acked
    if (lane == 0)
      __hip_atomic_store(myflag, (unsigned)t + 1u, __ATOMIC_RELAXED, __HIP_MEMORY_SCOPE_AGENT);
  }

  if (Hy32 != nullptr)
    *reinterpret_cast<f32x4*>(Hy32 + (size_t)rowG * 512 + colG) = hy;
}

// out[b][c] = sum_k hy[b][k] * Wout[k][c] + bout[c]
__global__ void cornn_out_kernel(const float* __restrict__ Hy32,
                                 const unsigned short* __restrict__ HbfFinal,
                                 const float* __restrict__ Wout,
                                 const float* __restrict__ bout,
                                 float* __restrict__ out) {
  const int b = blockIdx.x;
  const int lane = threadIdx.x;   // 64 threads
  float a[N_OUT];
  #pragma unroll
  for (int c = 0; c < N_OUT; ++c) a[c] = 0.f;
  #pragma unroll
  for (int j = 0; j < 8; ++j) {
    const int k = lane + (j << 6);
    const float h = Hy32 ? Hy32[(size_t)b * N_HID + k]
                         : bf2f(HbfFinal[(size_t)b * 1024 + 512 + k]);
    const float* wr = Wout + (size_t)k * N_OUT;
    #pragma unroll
    for (int c = 0; c < N_OUT; ++c) a[c] += h * wr[c];
  }
  #pragma unroll
  for (int c = 0; c < N_OUT; ++c) {
    float v = a[c];
    for (int off = 32; off > 0; off >>= 1) v += __shfl_down(v, off, 64);
    if (lane == 0) out[(size_t)b * N_OUT + c] = v + bout[c];
  }
}

extern "C" void kernel_launch(void* const* d_in, const int* in_sizes, int n_in,
                              void* d_out, int out_size, void* d_ws, size_t ws_size,
                              hipStream_t stream) {
  (void)in_sizes; (void)n_in; (void)out_size;
  const float* x    = (const float*)d_in[0];
  const float* W    = (const float*)d_in[1];
  const float* bias = (const float*)d_in[2];
  const float* Wout = (const float*)d_in[3];
  const float* bout = (const float*)d_in[4];

  char* ws = (char*)d_ws;
  unsigned*       flags = (unsigned*)ws;                      // 4 KiB flag area
  unsigned short* Hbf   = (unsigned short*)(ws + 4096);       // 2 x 256 x 1024 bf16 = 1 MiB
  float*          Hy32  = (float*)(ws + 4096 + (size_t)2 * 256 * 1024 * 2);
  const size_t needed = 4096 + (size_t)2 * 256 * 1024 * 2 + (size_t)256 * 512 * 4;
  float* hyPtr = (ws_size >= needed) ? Hy32 : nullptr;

  hipMemsetAsync(flags, 0, 4096, stream);   // flags = 0 (ws is re-poisoned each launch)

  cornn_kernel<<<dim3(NWG), dim3(WG_THREADS), 0, stream>>>(x, W, bias, Hbf, hyPtr, flags);

  cornn_out_kernel<<<dim3(BATCH), dim3(64), 0, stream>>>(hyPtr, Hbf, Wout, bout,
                                                         (float*)d_out);
}